// Round 5
// baseline (299.229 us; speedup 1.0000x reference)
//
#include <hip/hip_runtime.h>
#include <math.h>

// Problem constants: B=2, H=240, W=1216, ITER=3, NUM=9, CH=27
#define B_ 2
#define H_ 240
#define W_ 1216
#define CH_ 27
#define NUM_ 9
#define PIX_ (B_ * H_ * W_)   // 583680
#define TX 32
#define TY 8
#define HALO_W (TX + 2)       // 34
#define HALO_H (TY + 2)       // 10
#define NPX (HALO_H * HALO_W) // 340 pixels in the haloed tile
#define CHL 40                // bf16 per pixel in sG (80 B, 16B-aligned rows)
#define SCS 27                // sC stride (gcd(27,32)=1 -> conflict-free)

typedef __attribute__((ext_vector_type(8))) __bf16 bf16x8;
typedef __attribute__((ext_vector_type(16))) float f32x16;

union bfpack { __bf16 h[2]; unsigned int u; };

// ---------------------------------------------------------------------------
// Fully self-contained fused kernel (one per propagation iteration):
//  - stages guide tile straight from NCHW fp32 -> channel-major bf16 LDS
//  - builds its 18 MFMA B-fragments in LDS from conv_w (2 contiguous chunks)
//  - 9 shifted K=32 GEMMs via mfma_f32_32x32x16_bf16
//  - softmax + branchless 9-tap bilinear propagation + confidence blend
// Exactly 3 dispatches per call -> minimizes per-dispatch gap overhead.
// ---------------------------------------------------------------------------
__global__ __launch_bounds__(256, 3) void dyspn_iter_fused(
    const float* __restrict__ guide, const float* __restrict__ conv_w,
    const float* __restrict__ conv_b, const float* __restrict__ tap,
    const float* __restrict__ confidence, const float* __restrict__ sp_dep,
    const float* __restrict__ cur_in, float* __restrict__ out_cur,
    float* __restrict__ pred, float* __restrict__ feat,
    const float* __restrict__ input, int iter)
{
    // union region: sG [340][40] bf16 = 27200 B ; sC [256][27] f32 = 27648 B
    __shared__ __align__(16) char smemA[256 * SCS * 4];
    // B-fragment store: [tap*2+ks][lane][8] bf16 = 18432 B (separate, no alias)
    __shared__ __align__(16) __bf16 sW[18 * 64 * 8];
    __shared__ float sBias[CH_ + 1];
    __shared__ float sTap[18];

    __bf16*       sG   = (__bf16*)smemA;
    unsigned int* sG32 = (unsigned int*)smemA;
    float*        sC   = (float*)smemA;

    const int tid  = threadIdx.x;
    const int lane = tid & 63;
    const int w    = tid >> 6;       // wave id -> M-rows 2w, 2w+1
    const int xl   = lane & 31;
    const int half = lane >> 5;
    const int tileX0 = blockIdx.x * TX;
    const int tileY0 = blockIdx.y * TY;
    const int b      = blockIdx.z;

    const int x = tileX0 + (tid & 31);
    const int y = tileY0 + (tid >> 5);
    const int pix = b * (H_ * W_) + y * W_ + x;

    // early per-pixel loads: latency hides under staging + MFMA
    const float cpix  = confidence[pix];
    const float sppix = sp_dep[pix];
    const float inpix = input[pix];

    if (tid < CH_) {
        int n = tid;
        int oc = (n < 18) ? (iter * 18 + n) : (54 + iter * NUM_ + (n - 18));
        sBias[tid] = conv_b[oc];
    }
    if (tid >= 64 && tid < 64 + 18) sTap[tid - 64] = tap[tid - 64];

    // --- zero the B-frag pad slots (ic in [27,32): ks=1, half=1, j in [3,8)) ---
    // disjoint from filled slots -> no extra barrier needed
    for (int idx = tid; idx < 9 * 32 * 5; idx += 256) {
        int t9  = idx / 160;
        int r   = idx - t9 * 160;
        int l32 = r / 5;
        int j   = 3 + (r - l32 * 5);
        sW[(((t9 * 2 + 1) * 64) + 32 + l32) * 8 + j] = (__bf16)0.f;
    }

    // --- build B fragments from conv_w (two contiguous chunks, coalesced) ---
    // chunk0: 18*243 floats (offset channels), chunk1: 9*243 floats (aff)
    {
        const float* c0 = conv_w + (size_t)iter * 18 * 243;
        const float* c1 = conv_w + (size_t)(54 + iter * NUM_) * 243;
        for (int idx = tid; idx < 6561; idx += 256) {
            int n, rem; float v;
            if (idx < 4374) {
                n = idx / 243; rem = idx - n * 243; v = c0[idx];
            } else {
                int g = idx - 4374;
                int n2 = g / 243; rem = g - n2 * 243; n = 18 + n2; v = c1[g];
            }
            int ic = rem / 9;
            int tp = rem - ic * 9;
            int ks = ic >> 4;
            int rr = ic & 15;
            int hf = rr >> 3;
            int j  = rr & 7;
            sW[(((tp * 2 + ks) * 64) + hf * 32 + n) * 8 + j] = (__bf16)v;
        }
    }

    // --- stage guide tile from NCHW fp32 -> sG [p][CHL] bf16 (zero halo+pad) ---
    // p-fastest -> coalesced global loads; packed bf16x2 LDS writes
    for (int idx = tid; idx < NPX * 16; idx += 256) {
        int pair = idx / NPX;
        int p    = idx - pair * NPX;
        int row  = p / HALO_W;
        int px   = p - row * HALO_W;
        int gy = tileY0 + row - 1;
        int gx = tileX0 + px - 1;
        bool ib = (gx >= 0) && (gx < W_) && (gy >= 0) && (gy < H_);
        int ch0 = pair * 2;
        float v0 = 0.f, v1 = 0.f;
        if (ib && ch0 < CH_) {
            const float* base = guide + ((size_t)(b * CH_ + ch0) * H_ + gy) * W_ + gx;
            v0 = base[0];
            if (ch0 + 1 < CH_) v1 = base[(size_t)H_ * W_];
        }
        bfpack pk;
        pk.h[0] = (__bf16)v0;
        pk.h[1] = (__bf16)v1;
        sG32[p * (CHL / 2) + pair] = pk.u;
    }

    f32x16 acc0 = {0,0,0,0,0,0,0,0,0,0,0,0,0,0,0,0};
    f32x16 acc1 = {0,0,0,0,0,0,0,0,0,0,0,0,0,0,0,0};

    __syncthreads();

    // preload all 18 B fragments (one-time; sW dead afterwards)
    bf16x8 Bf[18];
    #pragma unroll
    for (int f = 0; f < 18; ++f)
        Bf[f] = *(const bf16x8*)(sW + ((size_t)(f * 64) + lane) * 8);

    // --- MFMA main loop: 24 ds_read_b128 + 36 MFMAs per wave ---
    #pragma unroll
    for (int kw = 0; kw < 3; ++kw) {
        #pragma unroll
        for (int ks = 0; ks < 2; ++ks) {
            bf16x8 A4[4];
            #pragma unroll
            for (int d = 0; d < 4; ++d) {
                const __bf16* ap = sG + (size_t)((2 * w + d) * HALO_W + xl + kw) * CHL
                                 + ks * 16 + half * 8;
                A4[d] = *(const bf16x8*)ap;
            }
            #pragma unroll
            for (int kh = 0; kh < 3; ++kh) {
                int t = kh * 3 + kw;
                acc0 = __builtin_amdgcn_mfma_f32_32x32x16_bf16(A4[kh],     Bf[t * 2 + ks], acc0, 0, 0, 0);
                acc1 = __builtin_amdgcn_mfma_f32_32x32x16_bf16(A4[kh + 1], Bf[t * 2 + ks], acc1, 0, 0, 0);
            }
        }
    }

    __syncthreads();   // all sG reads done before aliased sC writes

    // scatter C -> sC pixel-major [256][27]
    // C/D layout: ch = lane&31, px_x = (r&3) + 8*(r>>2) + 4*(lane>>5)
    if (xl < CH_) {
        #pragma unroll
        for (int a = 0; a < 2; ++a) {
            const f32x16 A = a ? acc1 : acc0;
            int ra = 2 * w + a;
            #pragma unroll
            for (int r = 0; r < 16; ++r) {
                int px_x = (r & 3) + 8 * (r >> 2) + 4 * half;
                sC[(ra * 32 + px_x) * SCS + xl] = A[r];
            }
        }
    }

    __syncthreads();

    // --- epilogue: one thread per pixel ---
    float v27[CH_];
    #pragma unroll
    for (int j = 0; j < CH_; ++j) v27[j] = sC[tid * SCS + j] + sBias[j];

    float m = v27[18];
    #pragma unroll
    for (int n = 1; n < 9; ++n) m = fmaxf(m, v27[18 + n]);
    float a9[9]; float s = 0.f;
    #pragma unroll
    for (int n = 0; n < 9; ++n) { a9[n] = __expf(v27[18 + n] - m); s += a9[n]; }
    const float inv_s = 1.f / s;

    // branchless bilinear: 36 unconditional clamped loads x validity masks
    const float* cur = cur_in + (size_t)b * (H_ * W_);
    float agg = 0.f;
    #pragma unroll
    for (int n = 0; n < 9; ++n) {
        float px = v27[2 * n]     + sTap[2 * n]     + (float)x;
        float py = v27[2 * n + 1] + sTap[2 * n + 1] + (float)y;
        float x0f = floorf(px), y0f = floorf(py);
        float wx = px - x0f, wy = py - y0f;
        int x0 = (int)x0f, y0 = (int)y0f;
        int cx0 = min(max(x0, 0), W_ - 1), cx1 = min(max(x0 + 1, 0), W_ - 1);
        int cy0 = min(max(y0, 0), H_ - 1), cy1 = min(max(y0 + 1, 0), H_ - 1);
        float mx0 = (x0 >= 0 && x0 < W_) ? 1.f : 0.f;
        float mx1 = (x0 + 1 >= 0 && x0 + 1 < W_) ? 1.f : 0.f;
        float my0 = (y0 >= 0 && y0 < H_) ? 1.f : 0.f;
        float my1 = (y0 + 1 >= 0 && y0 + 1 < H_) ? 1.f : 0.f;
        const float* r0 = cur + (size_t)cy0 * W_;
        const float* r1 = cur + (size_t)cy1 * W_;
        float v00 = r0[cx0] * (mx0 * my0);
        float v01 = r0[cx1] * (mx1 * my0);
        float v10 = r1[cx0] * (mx0 * my1);
        float v11 = r1[cx1] * (mx1 * my1);
        float val = (1.f - wy) * ((1.f - wx) * v00 + wx * v01)
                  +        wy  * ((1.f - wx) * v10 + wx * v11);
        agg = fmaf(val, a9[n] * inv_s, agg);
    }

    float sgn = (sppix > 0.f) ? 1.f : ((sppix < 0.f) ? -1.f : 0.f);
    float conf = sgn / (1.f + __expf(-cpix));
    float nc = (1.f - conf) * agg + conf * sppix;

    out_cur[pix] = nc;
    if (pred) pred[pix] = nc;
    if (feat) feat[pix] = inpix;
}

extern "C" void kernel_launch(void* const* d_in, const int* in_sizes, int n_in,
                              void* d_out, int out_size, void* d_ws, size_t ws_size,
                              hipStream_t stream) {
    (void)in_sizes; (void)n_in; (void)out_size; (void)d_ws; (void)ws_size;
    const float* input      = (const float*)d_in[0];
    const float* guide      = (const float*)d_in[1];
    const float* sp_dep     = (const float*)d_in[2];
    const float* confidence = (const float*)d_in[3];
    const float* conv_w     = (const float*)d_in[4];
    const float* conv_b     = (const float*)d_in[5];
    const float* tap        = (const float*)d_in[6];

    float* out   = (float*)d_out;
    const int P  = PIX_;
    float* pred  = out;           // [B,1,H,W]
    float* feat  = out + P;       // [B,1,H,W]
    float* inter = out + 2 * P;   // [ITER,B,1,H,W]

    dim3 grid(W_ / TX, H_ / TY, B_);  // 38 x 30 x 2
    dim3 block(256);

    for (int i = 0; i < 3; ++i) {
        const float* cur = (i == 0) ? input : (inter + (i - 1) * P);
        dyspn_iter_fused<<<grid, block, 0, stream>>>(
            guide, conv_w, conv_b, tap, confidence, sp_dep,
            cur, inter + i * P,
            (i == 2) ? pred : nullptr,
            (i == 0) ? feat : nullptr,
            input, i);
    }
}